// Round 13
// baseline (1141.458 us; speedup 1.0000x reference)
//
#include <hip/hip_runtime.h>
#include <math.h>

constexpr int F_IN = 20;
constexpr int DDIM = 256;

typedef __attribute__((ext_vector_type(8))) short bf16x8;
typedef __attribute__((ext_vector_type(4))) float f32x4;
typedef __attribute__((ext_vector_type(16))) float f32x16;

__device__ __forceinline__ float b2f(unsigned short u){
  union { unsigned int i; float f; } x; x.i = ((unsigned int)u) << 16; return x.f;
}
__device__ __forceinline__ unsigned short f2b(float f){
  union { float f; unsigned int i; } x; x.f = f;
  unsigned int r = x.i + 0x7fffu + ((x.i >> 16) & 1u);
  return (unsigned short)(r >> 16);
}

// ---------------- edge preprocessing ----------------
__global__ __launch_bounds__(256) void edge_prep_k(
    const int* __restrict__ ei, const float* __restrict__ pos,
    const float* __restrict__ mw1, const float* __restrict__ mb1,
    const float* __restrict__ mw2, const float* __restrict__ mb2,
    float* __restrict__ ew, int* __restrict__ cnt, int E)
{
  int t = blockIdx.x*256 + threadIdx.x;
  if (t >= E) return;
  int s = ei[t], d = ei[E + t];
  float dx = pos[s*3+0]-pos[d*3+0];
  float dy = pos[s*3+1]-pos[d*3+1];
  float dz = pos[s*3+2]-pos[d*3+2];
  float dist = sqrtf(dx*dx+dy*dy+dz*dz);
  float o = mb2[0];
  #pragma unroll
  for (int j=0;j<32;j++){
    float hj = fmaxf(dist*mw1[j]+mb1[j], 0.f);
    o += hj*mw2[j];
  }
  o = fmaxf(o, 0.f);
  ew[t] = o;
  atomicAdd(&cnt[d], 1);
}

// ---------------- scans (counting sort by dst) ----------------
__global__ __launch_bounds__(512) void scan1_k(const int* __restrict__ cnt, int* __restrict__ offs,
                                               int* __restrict__ bsum, int n)
{
  __shared__ int t[512];
  int tid = threadIdx.x;
  int i = blockIdx.x*512 + tid;
  int v = (i < n) ? cnt[i] : 0;
  t[tid] = v;
  __syncthreads();
  for (int s = 1; s < 512; s <<= 1) {
    int y = (tid >= s) ? t[tid - s] : 0;
    __syncthreads();
    if (tid >= s) t[tid] += y;
    __syncthreads();
  }
  if (i < n) offs[i] = t[tid] - v;
  if (tid == 511) bsum[blockIdx.x] = t[511];
}

__global__ __launch_bounds__(512) void scan2_k(const int* __restrict__ bsum, int* __restrict__ bpre, int nb)
{
  __shared__ int t[512];
  int tid = threadIdx.x;
  int v = (tid < nb) ? bsum[tid] : 0;
  t[tid] = v;
  __syncthreads();
  for (int s = 1; s < 512; s <<= 1) {
    int y = (tid >= s) ? t[tid - s] : 0;
    __syncthreads();
    if (tid >= s) t[tid] += y;
    __syncthreads();
  }
  bpre[tid] = t[tid] - v;
}

__global__ __launch_bounds__(512) void scan3_k(int* __restrict__ offs, int* __restrict__ cur,
                                               const int* __restrict__ bpre, int n, int e)
{
  int i = blockIdx.x*512 + threadIdx.x;
  if (i < n){
    int v = offs[i] + bpre[blockIdx.x];
    offs[i] = v;
    cur[i]  = v;                        // scatter cursor init (replaces d2d memcpy)
  }
  if (i == 0) offs[n] = e;
}

__global__ __launch_bounds__(256) void scatter_k(const int* __restrict__ ei, const float* __restrict__ ew,
    int* __restrict__ cur, int2* __restrict__ ssew, int E)
{
  int t = blockIdx.x*256 + threadIdx.x;
  if (t >= E) return;
  int d = ei[E+t];
  int p = atomicAdd(&cur[d], 1);
  int2 v; v.x = ei[t]; v.y = __float_as_int(ew[t]);
  ssew[p] = v;
}

// ---------------- graph segment offsets via binary search (batch sorted) ----------------
__global__ void gseg_k(const int* __restrict__ batch, int* __restrict__ goff, int n){
  int g = threadIdx.x;
  if (g > 64) return;
  int lo = 0, hi = n;
  while (lo < hi){ int mid = (lo + hi) >> 1; if (batch[mid] < g) lo = mid + 1; else hi = mid; }
  goff[g] = lo;
}

// ---------------- weight convert+transpose: Wt[layer][512 cols][256 k] bf16 ----------------
__global__ __launch_bounds__(256) void wt_k(const float* __restrict__ gwl, const float* __restrict__ gwr,
                                            unsigned short* __restrict__ Wt)
{
  __shared__ float t[64][65];
  int ct = blockIdx.x;
  int kt = blockIdx.y;
  int layer = blockIdx.z;
  int tid = threadIdx.x;
  int cbase = ct*64, k0 = kt*64;
  const float* src = (cbase < 256) ? (gwl + (size_t)layer*65536) : (gwr + (size_t)layer*65536);
  int csrc0 = (cbase < 256) ? cbase : cbase - 256;
  #pragma unroll
  for (int j = 0; j < 16; ++j){
    int idx = j*256 + tid;
    int kl = idx >> 6, cl = idx & 63;
    t[cl][kl] = src[(size_t)(k0 + kl)*256 + csrc0 + cl];
  }
  __syncthreads();
  #pragma unroll
  for (int j = 0; j < 16; ++j){
    int idx = j*256 + tid;
    int cl = idx >> 6, kl = idx & 63;
    Wt[(size_t)layer*131072 + (size_t)(cbase + cl)*256 + k0 + kl] = f2b(t[cl][kl]);
  }
}

// ---------------- h0 = x @ w_in + b_in (f32 + bf16 mirror) ----------------
__global__ __launch_bounds__(256) void h0_k(const float* __restrict__ x, const float* __restrict__ w,
    const float* __restrict__ b, float* __restrict__ h, unsigned short* __restrict__ hb, int n)
{
  __shared__ float xs[16][20];
  int row0 = blockIdx.x*16, tid = threadIdx.x;
  for (int idx = tid; idx < 16*20; idx += 256){
    int r = idx/20, c = idx%20;
    int rr = row0 + r;
    xs[r][c] = (rr < n) ? x[rr*20 + c] : 0.f;
  }
  __syncthreads();
  float bj = b[tid];
  float acc[16];
  #pragma unroll
  for (int r=0;r<16;r++) acc[r] = bj;
  for (int k=0;k<20;k++){
    float wv = w[k*256 + tid];
    #pragma unroll
    for (int r=0;r<16;r++) acc[r] += xs[r][k]*wv;
  }
  #pragma unroll
  for (int r=0;r<16;r++){
    int rr = row0 + r;
    if (rr < n){
      h[(size_t)rr*256 + tid] = acc[r];
      hb[(size_t)rr*256 + tid] = f2b(acc[r]);
    }
  }
}

// ---------------- bf16 MFMA GEMM (32x32x16): out[N][512] = hb[N][256] @ Wt^T + bias --------
// Per wave: 64x64 output as 2x2 of 32x32 tiles. Per 64-K-step: 16 MFMA (vs 32 for 16x16x32)
// at the same 16 ds_read_b128. C/D layout: col=lane&31, row=(reg&3)+8*(reg>>2)+4*(lane>>5).
// A/B layout: row/col=lane&31, k=(lane>>5)*8+j. LDS-staged coalesced store epilogue.
__global__ __launch_bounds__(256) void gemm_mfma_k(
    const unsigned short* __restrict__ hb,   // [n][256] bf16
    const unsigned short* __restrict__ Wt,   // [512][256] bf16 (col-major weights)
    const float* __restrict__ bl, const float* __restrict__ br,
    unsigned short* __restrict__ out,        // [n][512] bf16
    int n)
{
  __shared__ short S[16384];                 // As = S[0:8192), Bs = S[8192:16384)
  short* As = S;
  short* Bs = S + 8192;
  int tid = threadIdx.x;
  int lane = tid & 63, wid = tid >> 6;
  int wr = wid >> 1, wc = wid & 1;
  int row0 = blockIdx.x * 128;
  int col0 = blockIdx.y * 128;
  f32x16 acc[2][2] = {};

  for (int k0 = 0; k0 < 256; k0 += 64) {
    #pragma unroll
    for (int j = 0; j < 4; ++j) {
      int c = j*256 + tid;
      int r = c >> 3, q = c & 7;
      int rg = row0 + r; if (rg > n-1) rg = n-1;
      bf16x8 av = *(const bf16x8*)(hb + (size_t)rg*256 + k0 + q*8);
      bf16x8 bv = *(const bf16x8*)(Wt + (size_t)(col0 + r)*256 + k0 + q*8);
      int qs = (q ^ (r & 7)) * 8;
      *(bf16x8*)(As + r*64 + qs) = av;
      *(bf16x8*)(Bs + r*64 + qs) = bv;
    }
    __syncthreads();
    #pragma unroll
    for (int kk = 0; kk < 4; ++kk) {       // k16 sub-steps of the 64-K tile
      bf16x8 a[2], b[2];
      #pragma unroll
      for (int mi = 0; mi < 2; ++mi) {
        int r = wr*64 + mi*32 + (lane & 31);
        int q = (kk*2 + (lane >> 5)) ^ (r & 7);
        a[mi] = *(const bf16x8*)(As + r*64 + q*8);
      }
      #pragma unroll
      for (int ni = 0; ni < 2; ++ni) {
        int r = wc*64 + ni*32 + (lane & 31);
        int q = (kk*2 + (lane >> 5)) ^ (r & 7);
        b[ni] = *(const bf16x8*)(Bs + r*64 + q*8);
      }
      #pragma unroll
      for (int mi = 0; mi < 2; ++mi)
        #pragma unroll
        for (int ni = 0; ni < 2; ++ni)
          acc[mi][ni] = __builtin_amdgcn_mfma_f32_32x32x16_bf16(a[mi], b[ni], acc[mi][ni], 0, 0, 0);
    }
    __syncthreads();
  }

  // epilogue: bias + convert into LDS (128x128 bf16, reuses As/Bs), then coalesced stores
  const float* bias = (col0 < 256) ? bl : br;
  int cb = (col0 < 256) ? col0 : col0 - 256;
  unsigned short* Cs = (unsigned short*)S;
  #pragma unroll
  for (int ni = 0; ni < 2; ++ni) {
    int coff = wc*64 + ni*32 + (lane & 31);
    float bv = bias[cb + coff];
    #pragma unroll
    for (int mi = 0; mi < 2; ++mi) {
      int rb = wr*64 + mi*32 + 4*(lane >> 5);
      #pragma unroll
      for (int reg = 0; reg < 16; ++reg) {
        int crow = (reg & 3) + 8*(reg >> 2);
        Cs[(rb + crow)*128 + coff] = f2b(acc[mi][ni][reg] + bv);
      }
    }
  }
  __syncthreads();
  #pragma unroll
  for (int it = 0; it < 8; ++it) {           // 128 rows x 16 chunks(8 shorts) = 2048 / 256 thr
    int row = (tid >> 4) + it*16;            // 0..127
    int ch  = (tid & 15) * 8;                // short offset 0..120
    bf16x8 v = *(const bf16x8*)(Cs + row*128 + ch);
    int grow = row0 + row;
    if (grow < n) *(bf16x8*)(out + (size_t)grow*512 + col0 + ch) = v;
  }
}

// ---------------- fused GATv2: 4 edges/iter, 16 lanes/edge, per-head softmax ----------------
// (round-10 exact: VGPR 64 is the occupancy cliff; prefetch variants refuted in r7/r11)
__global__ __launch_bounds__(256) void gat_agg_k(
    const unsigned short* __restrict__ xlr,  // [n][512] bf16: cols 0-255 xl, 256-511 xr
    const int* __restrict__ offs, const int2* __restrict__ ssew,
    const float* __restrict__ we, const float* __restrict__ att, const float* __restrict__ bias,
    float* __restrict__ h, unsigned short* __restrict__ hb, float* __restrict__ hout,
    const float* __restrict__ gw, const float* __restrict__ gb, float* __restrict__ logit, int n)
{
  int wid = blockIdx.x*4 + (threadIdx.x >> 6);
  if (wid >= n) return;
  int lane = threadIdx.x & 63;
  int g = lane >> 4, l = lane & 15;
  int c0 = l*16;                       // this lane's 16 channels (single head l>>2)

  // per-lane params (f32)
  float xr[16], wef[16], atf[16];
  {
    const unsigned short* xrp = xlr + (size_t)wid*512 + 256 + c0;
    bf16x8 r0 = *(const bf16x8*)xrp;
    bf16x8 r1 = *(const bf16x8*)(xrp + 8);
    #pragma unroll
    for (int i=0;i<8;i++){ xr[i] = b2f((unsigned short)r0[i]); xr[8+i] = b2f((unsigned short)r1[i]); }
    #pragma unroll
    for (int q=0;q<4;q++){
      float4 wv = *(const float4*)(we + c0 + q*4);
      float4 av = *(const float4*)(att + c0 + q*4);
      wef[q*4+0]=wv.x; wef[q*4+1]=wv.y; wef[q*4+2]=wv.z; wef[q*4+3]=wv.w;
      atf[q*4+0]=av.x; atf[q*4+1]=av.y; atf[q*4+2]=av.z; atf[q*4+3]=av.w;
    }
  }

  float m = -1e30f, s = 0.f;
  float a[16];
  #pragma unroll
  for (int i=0;i<16;i++) a[i] = 0.f;

  int k = offs[wid] + g, kend = offs[wid+1];
  float ewv = 0.f;
  bf16x8 xa = {0,0,0,0,0,0,0,0};
  bf16x8 xb = {0,0,0,0,0,0,0,0};
  if (k < kend){
    int2 ep = ssew[k];
    ewv = __int_as_float(ep.y);
    const unsigned short* xp = xlr + ((size_t)(unsigned)ep.x << 9) + c0;
    xa = *(const bf16x8*)xp; xb = *(const bf16x8*)(xp + 8);
  }
  while (__any(k < kend)) {
    bool act = (k < kend);
    bf16x8 ca = xa, cb = xb; float ce = ewv;
    k += 4;
    if (k < kend){
      int2 ep = ssew[k];
      ewv = __int_as_float(ep.y);
      const unsigned short* xp = xlr + ((size_t)(unsigned)ep.x << 9) + c0;
      xa = *(const bf16x8*)xp; xb = *(const bf16x8*)(xp + 8);
    }
    float xjf[16];
    #pragma unroll
    for (int i=0;i<8;i++){ xjf[i] = b2f((unsigned short)ca[i]); xjf[8+i] = b2f((unsigned short)cb[i]); }
    float p = 0.f;
    #pragma unroll
    for (int i=0;i<16;i++){
      float t = fmaf(ce, wef[i], xjf[i] + xr[i]);
      t = fmaxf(t, 0.2f*t);
      p = fmaf(t, atf[i], p);
    }
    // PER-HEAD logit: reduce over the 4 lanes sharing this head (lane bits 0,1)
    p += __shfl_xor(p, 1);
    p += __shfl_xor(p, 2);
    if (!act) p = -1e30f;              // lanes past end contribute nothing
    if (__any(p > m + 8.f)) {
      float mn = fmaxf(m, p);
      float corr = __expf(m - mn);
      float wv = act ? __expf(p - mn) : 0.f;
      s = s*corr + wv;
      #pragma unroll
      for (int i=0;i<16;i++) a[i] = fmaf(a[i], corr, wv*xjf[i]);
      m = mn;
    } else {
      float wv = act ? __expf(p - m) : 0.f;
      s += wv;
      #pragma unroll
      for (int i=0;i<16;i++) a[i] = fmaf(wv, xjf[i], a[i]);
    }
  }

  // flash-merge the 4 edge-groups per head (butterfly over lane bits 4,5; per-lane state)
  #pragma unroll
  for (int d = 16; d <= 32; d <<= 1) {
    float mo = __shfl_xor(m, d);
    float so = __shfl_xor(s, d);
    float mn = fmaxf(m, mo);
    float cs = __expf(m - mn), co = __expf(mo - mn);
    s = s*cs + so*co;
    #pragma unroll
    for (int i=0;i<16;i++){
      float ao = __shfl_xor(a[i], d);
      a[i] = fmaf(a[i], cs, ao*co);
    }
    m = mn;
  }

  // epilogue: all 64 lanes write 4 contiguous channels (wave = contiguous 1KB)
  float inv = 1.f/(s + 1e-16f);        // this lane's head denominator
  float4 av;
  if (g == 0)      av = make_float4(a[0], a[1], a[2], a[3]);
  else if (g == 1) av = make_float4(a[4], a[5], a[6], a[7]);
  else if (g == 2) av = make_float4(a[8], a[9], a[10], a[11]);
  else             av = make_float4(a[12], a[13], a[14], a[15]);
  int cw = l*16 + g*4;
  size_t base = (size_t)wid*256 + cw;
  float4 hv = *(const float4*)(h + base);
  float4 b4 = *(const float4*)(bias + cw);
  float4 o;
  o.x = fmaxf(hv.x + av.x*inv + b4.x, 0.f);
  o.y = fmaxf(hv.y + av.y*inv + b4.y, 0.f);
  o.z = fmaxf(hv.z + av.z*inv + b4.z, 0.f);
  o.w = fmaxf(hv.w + av.w*inv + b4.w, 0.f);
  *(float4*)(h + base) = o;
  ushort4 ob;
  ob.x = f2b(o.x); ob.y = f2b(o.y); ob.z = f2b(o.z); ob.w = f2b(o.w);
  *(ushort4*)(hb + base) = ob;
  if (hout) *(float4*)(hout + base) = o;

  // fused pooling gate logit (only on pooling layers): dot(h_row, gate_w) over 256 ch
  if (gw) {
    float4 gv = *(const float4*)(gw + cw);
    float p = o.x*gv.x + o.y*gv.y + o.z*gv.z + o.w*gv.w;
    p += __shfl_xor(p, 1);
    p += __shfl_xor(p, 2);
    p += __shfl_xor(p, 4);
    p += __shfl_xor(p, 8);
    p += __shfl_xor(p, 16);
    p += __shfl_xor(p, 32);
    if (lane == 0) logit[wid] = p + gb[0];
  }
}

// ---------------- pooling: per-slice online-softmax partials, then merge ----------------
// part layout per (g,slice): [0]=m, [1]=s, [2..257]=acc  (260 floats stride)
__global__ __launch_bounds__(256) void pool1_k(const unsigned short* __restrict__ hb,
    const float* __restrict__ logit, const int* __restrict__ goff, float* __restrict__ part)
{
  __shared__ float red[256];
  int g = blockIdx.x >> 3, sl = blockIdx.x & 7;
  int b0 = goff[g], b1 = goff[g+1];
  int len = b1 - b0;
  int per = (len + 7) >> 3;
  int r0 = b0 + sl*per;
  int r1 = r0 + per; if (r1 > b1) r1 = b1;
  int tid = threadIdx.x;
  float* P = part + (size_t)blockIdx.x * 260;

  float lm = -1e30f;
  for (int i = r0 + tid; i < r1; i += 256) lm = fmaxf(lm, logit[i]);
  red[tid] = lm;
  __syncthreads();
  for (int s = 128; s > 0; s >>= 1){
    if (tid < s) red[tid] = fmaxf(red[tid], red[tid+s]);
    __syncthreads();
  }
  float m = red[0];
  __syncthreads();                       // all threads read red[0] before reuse
  float sw = 0.f;
  for (int i = r0 + tid; i < r1; i += 256) sw += __expf(logit[i] - m);
  red[tid] = sw;
  __syncthreads();
  for (int s = 128; s > 0; s >>= 1){
    if (tid < s) red[tid] += red[tid+s];
    __syncthreads();
  }
  float ssum = red[0];

  float acc = 0.f;
  for (int i = r0; i < r1; ++i)
    acc += __expf(logit[i] - m) * b2f(hb[(size_t)i*256 + tid]);
  P[2 + tid] = acc;
  if (tid == 0){ P[0] = m; P[1] = ssum; }
}

__global__ __launch_bounds__(256) void pool2_k(const float* __restrict__ part, float* __restrict__ hbar)
{
  int g = blockIdx.x, tid = threadIdx.x;
  const float* P = part + (size_t)g*8*260;
  float M = -1e30f;
  #pragma unroll
  for (int s = 0; s < 8; ++s) M = fmaxf(M, P[s*260]);
  float den = 0.f, acc = 0.f;
  #pragma unroll
  for (int s = 0; s < 8; ++s){
    float c = __expf(P[s*260] - M);
    den += P[s*260 + 1] * c;
    acc += P[s*260 + 2 + tid] * c;
  }
  hbar[g*256 + tid] = acc/(den + 1e-16f);
}

// ---------------- small row GEMM ----------------
template<int K, bool RELU>
__global__ __launch_bounds__(256) void rowgemm_k(const float* __restrict__ A, const float* __restrict__ W,
    const float* __restrict__ bias, float* __restrict__ out, int ostride)
{
  __shared__ float ar[K];
  int row = blockIdx.x;
  int tid = threadIdx.x;
  for (int i = tid; i < K; i += 256) ar[i] = A[(size_t)row*K + i];
  __syncthreads();
  float acc = bias[tid];
  for (int k = 0; k < K; ++k) acc += ar[k]*W[k*256 + tid];
  if (RELU) acc = fmaxf(acc, 0.f);
  out[(size_t)row*ostride + tid] = acc;
}

extern "C" void kernel_launch(void* const* d_in, const int* in_sizes, int n_in,
                              void* d_out, int out_size, void* d_ws, size_t ws_size,
                              hipStream_t stream)
{
  const float* x     = (const float*)d_in[0];
  const float* pos   = (const float*)d_in[1];
  const int*   ei    = (const int*)d_in[2];
  const int*   batch = (const int*)d_in[3];
  const float* mw1   = (const float*)d_in[4];
  const float* mb1   = (const float*)d_in[5];
  const float* mw2   = (const float*)d_in[6];
  const float* mb2   = (const float*)d_in[7];
  const float* w_in  = (const float*)d_in[8];
  const float* b_in  = (const float*)d_in[9];
  const float* gwl   = (const float*)d_in[10];
  const float* gbl   = (const float*)d_in[11];
  const float* gwr   = (const float*)d_in[12];
  const float* gbr   = (const float*)d_in[13];
  const float* gwe   = (const float*)d_in[14];
  const float* gatt  = (const float*)d_in[15];
  const float* gbias = (const float*)d_in[16];
  const float* gate_w= (const float*)d_in[17];
  const float* gate_b= (const float*)d_in[18];
  const float* nn_w  = (const float*)d_in[19];
  const float* nn_b  = (const float*)d_in[20];
  const float* ow1   = (const float*)d_in[21];
  const float* ob1   = (const float*)d_in[22];
  const float* ow2   = (const float*)d_in[23];
  const float* ob2   = (const float*)d_in[24];

  const int N = in_sizes[0] / F_IN;
  const int E = in_sizes[2] / 2;

  char* ws = (char*)d_ws;
  size_t woff = 0;
  auto alloc = [&](size_t bytes) -> void* {
    void* p = ws + woff;
    woff = (woff + bytes + 255) & ~(size_t)255;
    return p;
  };
  float* ew    = (float*)alloc((size_t)E*4);
  int*   cnt   = (int*)  alloc((size_t)N*4);
  int*   offs  = (int*)  alloc((size_t)(N+1)*4);
  int*   cur   = (int*)  alloc((size_t)N*4);
  int*   bsum  = (int*)  alloc(512*4);
  int*   bpre  = (int*)  alloc(512*4);
  int2*  ssew  = (int2*) alloc((size_t)E*8);
  float* h     = (float*)alloc((size_t)N*DDIM*4);
  unsigned short* hb  = (unsigned short*)alloc((size_t)N*DDIM*2);
  unsigned short* xlr = (unsigned short*)alloc((size_t)N*512*2);
  unsigned short* Wt  = (unsigned short*)alloc((size_t)6*512*256*2);
  float* logit = (float*)alloc((size_t)N*4);
  int*   goff  = (int*)  alloc(68*4);
  // pooling-phase scratch ALIASES the dead edge-MLP buffer (ew: E*4 = 3.2 MB;
  // ew is only live between edge_prep_k and scatter_k; these are only live in
  // the pooling phase). Keeps total ws usage at the round-5 passing footprint.
  float* part  = ew;                       // 512*260   = 133120 floats
  float* hbar  = ew + 133120;              // 64*256    =  16384 floats
  float* zcat  = ew + 149504;              // 64*768    =  49152 floats
  float* t1    = ew + 198656;              // 64*256    =  16384 floats (total 860 KB < 3.2 MB)
  (void)ws_size; (void)n_in; (void)out_size;

  hipMemsetAsync(cnt, 0, (size_t)N*4, stream);

  int eb = (E + 255)/256;
  edge_prep_k<<<eb, 256, 0, stream>>>(ei, pos, mw1, mb1, mw2, mb2, ew, cnt, E);
  int nb = (N + 511)/512;
  scan1_k<<<nb, 512, 0, stream>>>(cnt, offs, bsum, N);
  scan2_k<<<1, 512, 0, stream>>>(bsum, bpre, nb);
  scan3_k<<<nb, 512, 0, stream>>>(offs, cur, bpre, N, E);
  scatter_k<<<eb, 256, 0, stream>>>(ei, ew, cur, ssew, E);

  gseg_k<<<1, 128, 0, stream>>>(batch, goff, N);
  wt_k<<<dim3(8,4,6), 256, 0, stream>>>(gwl, gwr, Wt);

  h0_k<<<(N + 15)/16, 256, 0, stream>>>(x, w_in, b_in, h, hb, N);

  int gx = (N + 127)/128;
  int wavegrid = (N + 3)/4;
  for (int i = 0; i < 6; ++i) {
    gemm_mfma_k<<<dim3(gx, 4), 256, 0, stream>>>(hb, Wt + (size_t)i*131072,
        gbl + i*256, gbr + i*256, xlr, N);
    float* hout = (i == 5) ? (float*)d_out : (float*)nullptr;
    int blk = i >> 1;
    const float* gwp = (i & 1) ? (gate_w + blk*256) : (const float*)nullptr;
    const float* gbp = (i & 1) ? (gate_b + blk) : (const float*)nullptr;
    gat_agg_k<<<wavegrid, 256, 0, stream>>>(xlr, offs, ssew,
        gwe + i*256, gatt + i*256, gbias + i*256, h, hb, hout, gwp, gbp, logit, N);
    if (i & 1) {
      pool1_k<<<512, 256, 0, stream>>>(hb, logit, goff, part);
      pool2_k<<<64, 256, 0, stream>>>(part, hbar);
      rowgemm_k<256,false><<<64, 256, 0, stream>>>(hbar, nn_w + (size_t)blk*65536,
          nn_b + blk*256, zcat + blk*256, 768);
    }
  }
  rowgemm_k<768,true><<<64, 256, 0, stream>>>(zcat, ow1, ob1, t1, 256);
  rowgemm_k<256,false><<<64, 256, 0, stream>>>(t1, ow2, ob2, (float*)d_out + (size_t)N*DDIM, 256);
}

// Round 14
// 1119.512 us; speedup vs baseline: 1.0196x; 1.0196x over previous
//
#include <hip/hip_runtime.h>
#include <math.h>

constexpr int F_IN = 20;
constexpr int DDIM = 256;

typedef __attribute__((ext_vector_type(8))) short bf16x8;
typedef __attribute__((ext_vector_type(4))) float f32x4;

__device__ __forceinline__ float b2f(unsigned short u){
  union { unsigned int i; float f; } x; x.i = ((unsigned int)u) << 16; return x.f;
}
__device__ __forceinline__ unsigned short f2b(float f){
  union { float f; unsigned int i; } x; x.f = f;
  unsigned int r = x.i + 0x7fffu + ((x.i >> 16) & 1u);
  return (unsigned short)(r >> 16);
}

// ---------------- edge preprocessing ----------------
__global__ __launch_bounds__(256) void edge_prep_k(
    const int* __restrict__ ei, const float* __restrict__ pos,
    const float* __restrict__ mw1, const float* __restrict__ mb1,
    const float* __restrict__ mw2, const float* __restrict__ mb2,
    float* __restrict__ ew, int* __restrict__ cnt, int E)
{
  int t = blockIdx.x*256 + threadIdx.x;
  if (t >= E) return;
  int s = ei[t], d = ei[E + t];
  float dx = pos[s*3+0]-pos[d*3+0];
  float dy = pos[s*3+1]-pos[d*3+1];
  float dz = pos[s*3+2]-pos[d*3+2];
  float dist = sqrtf(dx*dx+dy*dy+dz*dz);
  float o = mb2[0];
  #pragma unroll
  for (int j=0;j<32;j++){
    float hj = fmaxf(dist*mw1[j]+mb1[j], 0.f);
    o += hj*mw2[j];
  }
  o = fmaxf(o, 0.f);
  ew[t] = o;
  atomicAdd(&cnt[d], 1);
}

// ---------------- scans (counting sort by dst) ----------------
__global__ __launch_bounds__(512) void scan1_k(const int* __restrict__ cnt, int* __restrict__ offs,
                                               int* __restrict__ bsum, int n)
{
  __shared__ int t[512];
  int tid = threadIdx.x;
  int i = blockIdx.x*512 + tid;
  int v = (i < n) ? cnt[i] : 0;
  t[tid] = v;
  __syncthreads();
  for (int s = 1; s < 512; s <<= 1) {
    int y = (tid >= s) ? t[tid - s] : 0;
    __syncthreads();
    if (tid >= s) t[tid] += y;
    __syncthreads();
  }
  if (i < n) offs[i] = t[tid] - v;
  if (tid == 511) bsum[blockIdx.x] = t[511];
}

__global__ __launch_bounds__(512) void scan2_k(const int* __restrict__ bsum, int* __restrict__ bpre, int nb)
{
  __shared__ int t[512];
  int tid = threadIdx.x;
  int v = (tid < nb) ? bsum[tid] : 0;
  t[tid] = v;
  __syncthreads();
  for (int s = 1; s < 512; s <<= 1) {
    int y = (tid >= s) ? t[tid - s] : 0;
    __syncthreads();
    if (tid >= s) t[tid] += y;
    __syncthreads();
  }
  bpre[tid] = t[tid] - v;
}

__global__ __launch_bounds__(512) void scan3_k(int* __restrict__ offs, int* __restrict__ cur,
                                               const int* __restrict__ bpre, int n, int e)
{
  int i = blockIdx.x*512 + threadIdx.x;
  if (i < n){
    int v = offs[i] + bpre[blockIdx.x];
    offs[i] = v;
    cur[i]  = v;                        // scatter cursor init (replaces d2d memcpy)
  }
  if (i == 0) offs[n] = e;
}

__global__ __launch_bounds__(256) void scatter_k(const int* __restrict__ ei, const float* __restrict__ ew,
    int* __restrict__ cur, int2* __restrict__ ssew, int E)
{
  int t = blockIdx.x*256 + threadIdx.x;
  if (t >= E) return;
  int d = ei[E+t];
  int p = atomicAdd(&cur[d], 1);
  int2 v; v.x = ei[t]; v.y = __float_as_int(ew[t]);
  ssew[p] = v;
}

// ---------------- graph segment offsets via binary search (batch sorted) ----------------
__global__ void gseg_k(const int* __restrict__ batch, int* __restrict__ goff, int n){
  int g = threadIdx.x;
  if (g > 64) return;
  int lo = 0, hi = n;
  while (lo < hi){ int mid = (lo + hi) >> 1; if (batch[mid] < g) lo = mid + 1; else hi = mid; }
  goff[g] = lo;
}

// ---------------- weight convert+transpose: Wt[layer][512 cols][256 k] bf16 ----------------
__global__ __launch_bounds__(256) void wt_k(const float* __restrict__ gwl, const float* __restrict__ gwr,
                                            unsigned short* __restrict__ Wt)
{
  __shared__ float t[64][65];
  int ct = blockIdx.x;
  int kt = blockIdx.y;
  int layer = blockIdx.z;
  int tid = threadIdx.x;
  int cbase = ct*64, k0 = kt*64;
  const float* src = (cbase < 256) ? (gwl + (size_t)layer*65536) : (gwr + (size_t)layer*65536);
  int csrc0 = (cbase < 256) ? cbase : cbase - 256;
  #pragma unroll
  for (int j = 0; j < 16; ++j){
    int idx = j*256 + tid;
    int kl = idx >> 6, cl = idx & 63;
    t[cl][kl] = src[(size_t)(k0 + kl)*256 + csrc0 + cl];
  }
  __syncthreads();
  #pragma unroll
  for (int j = 0; j < 16; ++j){
    int idx = j*256 + tid;
    int cl = idx >> 6, kl = idx & 63;
    Wt[(size_t)layer*131072 + (size_t)(cbase + cl)*256 + k0 + kl] = f2b(t[cl][kl]);
  }
}

// ---------------- h0 = x @ w_in + b_in (f32 + bf16 mirror) ----------------
__global__ __launch_bounds__(256) void h0_k(const float* __restrict__ x, const float* __restrict__ w,
    const float* __restrict__ b, float* __restrict__ h, unsigned short* __restrict__ hb, int n)
{
  __shared__ float xs[16][20];
  int row0 = blockIdx.x*16, tid = threadIdx.x;
  for (int idx = tid; idx < 16*20; idx += 256){
    int r = idx/20, c = idx%20;
    int rr = row0 + r;
    xs[r][c] = (rr < n) ? x[rr*20 + c] : 0.f;
  }
  __syncthreads();
  float bj = b[tid];
  float acc[16];
  #pragma unroll
  for (int r=0;r<16;r++) acc[r] = bj;
  for (int k=0;k<20;k++){
    float wv = w[k*256 + tid];
    #pragma unroll
    for (int r=0;r<16;r++) acc[r] += xs[r][k]*wv;
  }
  #pragma unroll
  for (int r=0;r<16;r++){
    int rr = row0 + r;
    if (rr < n){
      h[(size_t)rr*256 + tid] = acc[r];
      hb[(size_t)rr*256 + tid] = f2b(acc[r]);
    }
  }
}

// ---------------- bf16 MFMA GEMM (16x16x32, round-12 exact): out = hb @ Wt^T + bias --------
// LDS-staged epilogue: C -> LDS (reusing As/Bs after last barrier) -> coalesced 16B stores.
__global__ __launch_bounds__(256) void gemm_mfma_k(
    const unsigned short* __restrict__ hb,   // [n][256] bf16
    const unsigned short* __restrict__ Wt,   // [512][256] bf16 (col-major weights)
    const float* __restrict__ bl, const float* __restrict__ br,
    unsigned short* __restrict__ out,        // [n][512] bf16
    int n)
{
  __shared__ short S[16384];                 // As = S[0:8192), Bs = S[8192:16384)
  short* As = S;
  short* Bs = S + 8192;
  int tid = threadIdx.x;
  int lane = tid & 63, wid = tid >> 6;
  int wr = wid >> 1, wc = wid & 1;
  int row0 = blockIdx.x * 128;
  int col0 = blockIdx.y * 128;
  f32x4 acc[4][4] = {};

  for (int k0 = 0; k0 < 256; k0 += 64) {
    #pragma unroll
    for (int j = 0; j < 4; ++j) {
      int c = j*256 + tid;
      int r = c >> 3, q = c & 7;
      int rg = row0 + r; if (rg > n-1) rg = n-1;
      bf16x8 av = *(const bf16x8*)(hb + (size_t)rg*256 + k0 + q*8);
      bf16x8 bv = *(const bf16x8*)(Wt + (size_t)(col0 + r)*256 + k0 + q*8);
      int qs = (q ^ (r & 7)) * 8;
      *(bf16x8*)(As + r*64 + qs) = av;
      *(bf16x8*)(Bs + r*64 + qs) = bv;
    }
    __syncthreads();
    #pragma unroll
    for (int kk = 0; kk < 2; ++kk) {
      bf16x8 a[4], b[4];
      #pragma unroll
      for (int mi = 0; mi < 4; ++mi) {
        int r = wr*64 + mi*16 + (lane & 15);
        int q = (kk*4 + (lane >> 4)) ^ (r & 7);
        a[mi] = *(const bf16x8*)(As + r*64 + q*8);
      }
      #pragma unroll
      for (int ni = 0; ni < 4; ++ni) {
        int r = wc*64 + ni*16 + (lane & 15);
        int q = (kk*4 + (lane >> 4)) ^ (r & 7);
        b[ni] = *(const bf16x8*)(Bs + r*64 + q*8);
      }
      #pragma unroll
      for (int mi = 0; mi < 4; ++mi)
        #pragma unroll
        for (int ni = 0; ni < 4; ++ni)
          acc[mi][ni] = __builtin_amdgcn_mfma_f32_16x16x32_bf16(a[mi], b[ni], acc[mi][ni], 0, 0, 0);
    }
    __syncthreads();
  }

  // epilogue: bias + convert into LDS (128x128 bf16, reuses As/Bs), then coalesced stores
  const float* bias = (col0 < 256) ? bl : br;
  int cb = (col0 < 256) ? col0 : col0 - 256;
  unsigned short* Cs = (unsigned short*)S;
  #pragma unroll
  for (int ni = 0; ni < 4; ++ni) {
    int coff = wc*64 + ni*16 + (lane & 15);
    float bv = bias[cb + coff];
    #pragma unroll
    for (int mi = 0; mi < 4; ++mi) {
      int rbase = wr*64 + mi*16 + (lane >> 4)*4;
      #pragma unroll
      for (int e = 0; e < 4; ++e)
        Cs[(rbase + e)*128 + coff] = f2b(acc[mi][ni][e] + bv);
    }
  }
  __syncthreads();
  #pragma unroll
  for (int it = 0; it < 8; ++it) {           // 128 rows x 16 chunks(8 shorts) = 2048 / 256 thr
    int row = (tid >> 4) + it*16;            // 0..127
    int ch  = (tid & 15) * 8;                // short offset 0..120
    bf16x8 v = *(const bf16x8*)(Cs + row*128 + ch);
    int grow = row0 + row;
    if (grow < n) *(bf16x8*)(out + (size_t)grow*512 + col0 + ch) = v;
  }
}

// ---------------- fused GATv2: 4 edges/iter, 16 lanes/edge, per-head softmax ----------------
// (round-10 exact: VGPR 64 is the occupancy cliff; prefetch variants refuted in r7/r11)
__global__ __launch_bounds__(256) void gat_agg_k(
    const unsigned short* __restrict__ xlr,  // [n][512] bf16: cols 0-255 xl, 256-511 xr
    const int* __restrict__ offs, const int2* __restrict__ ssew,
    const float* __restrict__ we, const float* __restrict__ att, const float* __restrict__ bias,
    float* __restrict__ h, unsigned short* __restrict__ hb, float* __restrict__ hout,
    const float* __restrict__ gw, const float* __restrict__ gb, float* __restrict__ logit, int n)
{
  int wid = blockIdx.x*4 + (threadIdx.x >> 6);
  if (wid >= n) return;
  int lane = threadIdx.x & 63;
  int g = lane >> 4, l = lane & 15;
  int c0 = l*16;                       // this lane's 16 channels (single head l>>2)

  // per-lane params (f32)
  float xr[16], wef[16], atf[16];
  {
    const unsigned short* xrp = xlr + (size_t)wid*512 + 256 + c0;
    bf16x8 r0 = *(const bf16x8*)xrp;
    bf16x8 r1 = *(const bf16x8*)(xrp + 8);
    #pragma unroll
    for (int i=0;i<8;i++){ xr[i] = b2f((unsigned short)r0[i]); xr[8+i] = b2f((unsigned short)r1[i]); }
    #pragma unroll
    for (int q=0;q<4;q++){
      float4 wv = *(const float4*)(we + c0 + q*4);
      float4 av = *(const float4*)(att + c0 + q*4);
      wef[q*4+0]=wv.x; wef[q*4+1]=wv.y; wef[q*4+2]=wv.z; wef[q*4+3]=wv.w;
      atf[q*4+0]=av.x; atf[q*4+1]=av.y; atf[q*4+2]=av.z; atf[q*4+3]=av.w;
    }
  }

  float m = -1e30f, s = 0.f;
  float a[16];
  #pragma unroll
  for (int i=0;i<16;i++) a[i] = 0.f;

  int k = offs[wid] + g, kend = offs[wid+1];
  float ewv = 0.f;
  bf16x8 xa = {0,0,0,0,0,0,0,0};
  bf16x8 xb = {0,0,0,0,0,0,0,0};
  if (k < kend){
    int2 ep = ssew[k];
    ewv = __int_as_float(ep.y);
    const unsigned short* xp = xlr + ((size_t)(unsigned)ep.x << 9) + c0;
    xa = *(const bf16x8*)xp; xb = *(const bf16x8*)(xp + 8);
  }
  while (__any(k < kend)) {
    bool act = (k < kend);
    bf16x8 ca = xa, cb = xb; float ce = ewv;
    k += 4;
    if (k < kend){
      int2 ep = ssew[k];
      ewv = __int_as_float(ep.y);
      const unsigned short* xp = xlr + ((size_t)(unsigned)ep.x << 9) + c0;
      xa = *(const bf16x8*)xp; xb = *(const bf16x8*)(xp + 8);
    }
    float xjf[16];
    #pragma unroll
    for (int i=0;i<8;i++){ xjf[i] = b2f((unsigned short)ca[i]); xjf[8+i] = b2f((unsigned short)cb[i]); }
    float p = 0.f;
    #pragma unroll
    for (int i=0;i<16;i++){
      float t = fmaf(ce, wef[i], xjf[i] + xr[i]);
      t = fmaxf(t, 0.2f*t);
      p = fmaf(t, atf[i], p);
    }
    // PER-HEAD logit: reduce over the 4 lanes sharing this head (lane bits 0,1)
    p += __shfl_xor(p, 1);
    p += __shfl_xor(p, 2);
    if (!act) p = -1e30f;              // lanes past end contribute nothing
    if (__any(p > m + 8.f)) {
      float mn = fmaxf(m, p);
      float corr = __expf(m - mn);
      float wv = act ? __expf(p - mn) : 0.f;
      s = s*corr + wv;
      #pragma unroll
      for (int i=0;i<16;i++) a[i] = fmaf(a[i], corr, wv*xjf[i]);
      m = mn;
    } else {
      float wv = act ? __expf(p - m) : 0.f;
      s += wv;
      #pragma unroll
      for (int i=0;i<16;i++) a[i] = fmaf(wv, xjf[i], a[i]);
    }
  }

  // flash-merge the 4 edge-groups per head (butterfly over lane bits 4,5; per-lane state)
  #pragma unroll
  for (int d = 16; d <= 32; d <<= 1) {
    float mo = __shfl_xor(m, d);
    float so = __shfl_xor(s, d);
    float mn = fmaxf(m, mo);
    float cs = __expf(m - mn), co = __expf(mo - mn);
    s = s*cs + so*co;
    #pragma unroll
    for (int i=0;i<16;i++){
      float ao = __shfl_xor(a[i], d);
      a[i] = fmaf(a[i], cs, ao*co);
    }
    m = mn;
  }

  // epilogue: all 64 lanes write 4 contiguous channels (wave = contiguous 1KB)
  float inv = 1.f/(s + 1e-16f);        // this lane's head denominator
  float4 av;
  if (g == 0)      av = make_float4(a[0], a[1], a[2], a[3]);
  else if (g == 1) av = make_float4(a[4], a[5], a[6], a[7]);
  else if (g == 2) av = make_float4(a[8], a[9], a[10], a[11]);
  else             av = make_float4(a[12], a[13], a[14], a[15]);
  int cw = l*16 + g*4;
  size_t base = (size_t)wid*256 + cw;
  float4 hv = *(const float4*)(h + base);
  float4 b4 = *(const float4*)(bias + cw);
  float4 o;
  o.x = fmaxf(hv.x + av.x*inv + b4.x, 0.f);
  o.y = fmaxf(hv.y + av.y*inv + b4.y, 0.f);
  o.z = fmaxf(hv.z + av.z*inv + b4.z, 0.f);
  o.w = fmaxf(hv.w + av.w*inv + b4.w, 0.f);
  *(float4*)(h + base) = o;
  ushort4 ob;
  ob.x = f2b(o.x); ob.y = f2b(o.y); ob.z = f2b(o.z); ob.w = f2b(o.w);
  *(ushort4*)(hb + base) = ob;
  if (hout) *(float4*)(hout + base) = o;

  // fused pooling gate logit (only on pooling layers): dot(h_row, gate_w) over 256 ch
  if (gw) {
    float4 gv = *(const float4*)(gw + cw);
    float p = o.x*gv.x + o.y*gv.y + o.z*gv.z + o.w*gv.w;
    p += __shfl_xor(p, 1);
    p += __shfl_xor(p, 2);
    p += __shfl_xor(p, 4);
    p += __shfl_xor(p, 8);
    p += __shfl_xor(p, 16);
    p += __shfl_xor(p, 32);
    if (lane == 0) logit[wid] = p + gb[0];
  }
}

// ---------------- pooling stage 1: per-slice online-softmax partials ----------------
// part layout per (g,slice): [0]=m, [1]=s, [2..257]=acc  (260 floats stride)
__global__ __launch_bounds__(256) void pool1_k(const unsigned short* __restrict__ hb,
    const float* __restrict__ logit, const int* __restrict__ goff, float* __restrict__ part)
{
  __shared__ float red[256];
  int g = blockIdx.x >> 3, sl = blockIdx.x & 7;
  int b0 = goff[g], b1 = goff[g+1];
  int len = b1 - b0;
  int per = (len + 7) >> 3;
  int r0 = b0 + sl*per;
  int r1 = r0 + per; if (r1 > b1) r1 = b1;
  int tid = threadIdx.x;
  float* P = part + (size_t)blockIdx.x * 260;

  float lm = -1e30f;
  for (int i = r0 + tid; i < r1; i += 256) lm = fmaxf(lm, logit[i]);
  red[tid] = lm;
  __syncthreads();
  for (int s = 128; s > 0; s >>= 1){
    if (tid < s) red[tid] = fmaxf(red[tid], red[tid+s]);
    __syncthreads();
  }
  float m = red[0];
  __syncthreads();                       // all threads read red[0] before reuse
  float sw = 0.f;
  for (int i = r0 + tid; i < r1; i += 256) sw += __expf(logit[i] - m);
  red[tid] = sw;
  __syncthreads();
  for (int s = 128; s > 0; s >>= 1){
    if (tid < s) red[tid] += red[tid+s];
    __syncthreads();
  }
  float ssum = red[0];

  float acc = 0.f;
  for (int i = r0; i < r1; ++i)
    acc += __expf(logit[i] - m) * b2f(hb[(size_t)i*256 + tid]);
  P[2 + tid] = acc;
  if (tid == 0){ P[0] = m; P[1] = ssum; }
}

// ---------------- pooling stage 2 FUSED with nn Linear: zcat_blk[g] = pool(g) @ W + b -----
__global__ __launch_bounds__(256) void pool2nn_k(const float* __restrict__ part,
    const float* __restrict__ W, const float* __restrict__ b,
    float* __restrict__ out, int ostride)
{
  __shared__ float hs[256];
  int g = blockIdx.x, tid = threadIdx.x;
  const float* P = part + (size_t)g*8*260;
  float M = -1e30f;
  #pragma unroll
  for (int s = 0; s < 8; ++s) M = fmaxf(M, P[s*260]);
  float den = 0.f, acc = 0.f;
  #pragma unroll
  for (int s = 0; s < 8; ++s){
    float c = __expf(P[s*260] - M);
    den += P[s*260 + 1] * c;
    acc += P[s*260 + 2 + tid] * c;
  }
  hs[tid] = acc/(den + 1e-16f);
  __syncthreads();
  float o = b[tid];
  for (int k = 0; k < 256; ++k) o = fmaf(hs[k], W[k*256 + tid], o);
  out[(size_t)g*ostride + tid] = o;
}

// ---------------- fused output MLP: enc = relu(zcat @ ow1 + ob1) @ ow2 + ob2 --------------
__global__ __launch_bounds__(256) void outmlp_k(const float* __restrict__ zcat,
    const float* __restrict__ ow1, const float* __restrict__ ob1,
    const float* __restrict__ ow2, const float* __restrict__ ob2,
    float* __restrict__ out)
{
  __shared__ float zr[768];
  __shared__ float t1[256];
  int row = blockIdx.x, tid = threadIdx.x;
  for (int i = tid; i < 768; i += 256) zr[i] = zcat[(size_t)row*768 + i];
  __syncthreads();
  float a = ob1[tid];
  for (int k = 0; k < 768; ++k) a = fmaf(zr[k], ow1[k*256 + tid], a);
  t1[tid] = fmaxf(a, 0.f);
  __syncthreads();
  float o = ob2[tid];
  for (int k = 0; k < 256; ++k) o = fmaf(t1[k], ow2[k*256 + tid], o);
  out[(size_t)row*256 + tid] = o;
}

extern "C" void kernel_launch(void* const* d_in, const int* in_sizes, int n_in,
                              void* d_out, int out_size, void* d_ws, size_t ws_size,
                              hipStream_t stream)
{
  const float* x     = (const float*)d_in[0];
  const float* pos   = (const float*)d_in[1];
  const int*   ei    = (const int*)d_in[2];
  const int*   batch = (const int*)d_in[3];
  const float* mw1   = (const float*)d_in[4];
  const float* mb1   = (const float*)d_in[5];
  const float* mw2   = (const float*)d_in[6];
  const float* mb2   = (const float*)d_in[7];
  const float* w_in  = (const float*)d_in[8];
  const float* b_in  = (const float*)d_in[9];
  const float* gwl   = (const float*)d_in[10];
  const float* gbl   = (const float*)d_in[11];
  const float* gwr   = (const float*)d_in[12];
  const float* gbr   = (const float*)d_in[13];
  const float* gwe   = (const float*)d_in[14];
  const float* gatt  = (const float*)d_in[15];
  const float* gbias = (const float*)d_in[16];
  const float* gate_w= (const float*)d_in[17];
  const float* gate_b= (const float*)d_in[18];
  const float* nn_w  = (const float*)d_in[19];
  const float* nn_b  = (const float*)d_in[20];
  const float* ow1   = (const float*)d_in[21];
  const float* ob1   = (const float*)d_in[22];
  const float* ow2   = (const float*)d_in[23];
  const float* ob2   = (const float*)d_in[24];

  const int N = in_sizes[0] / F_IN;
  const int E = in_sizes[2] / 2;

  char* ws = (char*)d_ws;
  size_t woff = 0;
  auto alloc = [&](size_t bytes) -> void* {
    void* p = ws + woff;
    woff = (woff + bytes + 255) & ~(size_t)255;
    return p;
  };
  float* ew    = (float*)alloc((size_t)E*4);
  int*   cnt   = (int*)  alloc((size_t)N*4);
  int*   offs  = (int*)  alloc((size_t)(N+1)*4);
  int*   cur   = (int*)  alloc((size_t)N*4);
  int*   bsum  = (int*)  alloc(512*4);
  int*   bpre  = (int*)  alloc(512*4);
  int2*  ssew  = (int2*) alloc((size_t)E*8);
  float* h     = (float*)alloc((size_t)N*DDIM*4);
  unsigned short* hb  = (unsigned short*)alloc((size_t)N*DDIM*2);
  unsigned short* xlr = (unsigned short*)alloc((size_t)N*512*2);
  unsigned short* Wt  = (unsigned short*)alloc((size_t)6*512*256*2);
  float* logit = (float*)alloc((size_t)N*4);
  int*   goff  = (int*)  alloc(68*4);
  // pooling-phase scratch ALIASES the dead edge-MLP buffer (ew: E*4 = 3.2 MB;
  // ew is only live between edge_prep_k and scatter_k; these are only live in
  // the pooling phase). Keeps total ws usage at the round-5 passing footprint.
  float* part  = ew;                       // 512*260   = 133120 floats
  float* zcat  = ew + 149504;              // 64*768    =  49152 floats
  (void)ws_size; (void)n_in; (void)out_size;

  hipMemsetAsync(cnt, 0, (size_t)N*4, stream);

  int eb = (E + 255)/256;
  edge_prep_k<<<eb, 256, 0, stream>>>(ei, pos, mw1, mb1, mw2, mb2, ew, cnt, E);
  int nb = (N + 511)/512;
  scan1_k<<<nb, 512, 0, stream>>>(cnt, offs, bsum, N);
  scan2_k<<<1, 512, 0, stream>>>(bsum, bpre, nb);
  scan3_k<<<nb, 512, 0, stream>>>(offs, cur, bpre, N, E);
  scatter_k<<<eb, 256, 0, stream>>>(ei, ew, cur, ssew, E);

  gseg_k<<<1, 128, 0, stream>>>(batch, goff, N);
  wt_k<<<dim3(8,4,6), 256, 0, stream>>>(gwl, gwr, Wt);

  h0_k<<<(N + 15)/16, 256, 0, stream>>>(x, w_in, b_in, h, hb, N);

  int gx = (N + 127)/128;
  int wavegrid = (N + 3)/4;
  for (int i = 0; i < 6; ++i) {
    gemm_mfma_k<<<dim3(gx, 4), 256, 0, stream>>>(hb, Wt + (size_t)i*131072,
        gbl + i*256, gbr + i*256, xlr, N);
    float* hout = (i == 5) ? (float*)d_out : (float*)nullptr;
    int blk = i >> 1;
    const float* gwp = (i & 1) ? (gate_w + blk*256) : (const float*)nullptr;
    const float* gbp = (i & 1) ? (gate_b + blk) : (const float*)nullptr;
    gat_agg_k<<<wavegrid, 256, 0, stream>>>(xlr, offs, ssew,
        gwe + i*256, gatt + i*256, gbias + i*256, h, hb, hout, gwp, gbp, logit, N);
    if (i & 1) {
      pool1_k<<<512, 256, 0, stream>>>(hb, logit, goff, part);
      pool2nn_k<<<64, 256, 0, stream>>>(part, nn_w + (size_t)blk*65536,
          nn_b + blk*256, zcat + blk*256, 768);
    }
  }
  outmlp_k<<<64, 256, 0, stream>>>(zcat, ow1, ob1, ow2, ob2, (float*)d_out + (size_t)N*DDIM);
}

// Round 15
// 1095.758 us; speedup vs baseline: 1.0417x; 1.0217x over previous
//
#include <hip/hip_runtime.h>
#include <math.h>

constexpr int F_IN = 20;
constexpr int DDIM = 256;

typedef __attribute__((ext_vector_type(8))) short bf16x8;
typedef __attribute__((ext_vector_type(4))) float f32x4;

__device__ __forceinline__ float b2f(unsigned short u){
  union { unsigned int i; float f; } x; x.i = ((unsigned int)u) << 16; return x.f;
}
__device__ __forceinline__ unsigned short f2b(float f){
  union { float f; unsigned int i; } x; x.f = f;
  unsigned int r = x.i + 0x7fffu + ((x.i >> 16) & 1u);
  return (unsigned short)(r >> 16);
}

// ---------------- edge preprocessing ----------------
__global__ __launch_bounds__(256) void edge_prep_k(
    const int* __restrict__ ei, const float* __restrict__ pos,
    const float* __restrict__ mw1, const float* __restrict__ mb1,
    const float* __restrict__ mw2, const float* __restrict__ mb2,
    float* __restrict__ ew, int* __restrict__ cnt, int E)
{
  int t = blockIdx.x*256 + threadIdx.x;
  if (t >= E) return;
  int s = ei[t], d = ei[E + t];
  float dx = pos[s*3+0]-pos[d*3+0];
  float dy = pos[s*3+1]-pos[d*3+1];
  float dz = pos[s*3+2]-pos[d*3+2];
  float dist = sqrtf(dx*dx+dy*dy+dz*dz);
  float o = mb2[0];
  #pragma unroll
  for (int j=0;j<32;j++){
    float hj = fmaxf(dist*mw1[j]+mb1[j], 0.f);
    o += hj*mw2[j];
  }
  o = fmaxf(o, 0.f);
  ew[t] = o;
  atomicAdd(&cnt[d], 1);
}

// ---------------- scans (counting sort by dst) ----------------
__global__ __launch_bounds__(512) void scan1_k(const int* __restrict__ cnt, int* __restrict__ offs,
                                               int* __restrict__ bsum, int n)
{
  __shared__ int t[512];
  int tid = threadIdx.x;
  int i = blockIdx.x*512 + tid;
  int v = (i < n) ? cnt[i] : 0;
  t[tid] = v;
  __syncthreads();
  for (int s = 1; s < 512; s <<= 1) {
    int y = (tid >= s) ? t[tid - s] : 0;
    __syncthreads();
    if (tid >= s) t[tid] += y;
    __syncthreads();
  }
  if (i < n) offs[i] = t[tid] - v;
  if (tid == 511) bsum[blockIdx.x] = t[511];
}

__global__ __launch_bounds__(512) void scan2_k(const int* __restrict__ bsum, int* __restrict__ bpre, int nb)
{
  __shared__ int t[512];
  int tid = threadIdx.x;
  int v = (tid < nb) ? bsum[tid] : 0;
  t[tid] = v;
  __syncthreads();
  for (int s = 1; s < 512; s <<= 1) {
    int y = (tid >= s) ? t[tid - s] : 0;
    __syncthreads();
    if (tid >= s) t[tid] += y;
    __syncthreads();
  }
  bpre[tid] = t[tid] - v;
}

__global__ __launch_bounds__(512) void scan3_k(int* __restrict__ offs, int* __restrict__ cur,
                                               const int* __restrict__ bpre, int n, int e)
{
  int i = blockIdx.x*512 + threadIdx.x;
  if (i < n){
    int v = offs[i] + bpre[blockIdx.x];
    offs[i] = v;
    cur[i]  = v;                        // scatter cursor init (replaces d2d memcpy)
  }
  if (i == 0) offs[n] = e;
}

__global__ __launch_bounds__(256) void scatter_k(const int* __restrict__ ei, const float* __restrict__ ew,
    int* __restrict__ cur, int2* __restrict__ ssew, int E)
{
  int t = blockIdx.x*256 + threadIdx.x;
  if (t >= E) return;
  int d = ei[E+t];
  int p = atomicAdd(&cur[d], 1);
  int2 v; v.x = ei[t]; v.y = __float_as_int(ew[t]);
  ssew[p] = v;
}

// ---------------- graph segment offsets via binary search (batch sorted) ----------------
__global__ void gseg_k(const int* __restrict__ batch, int* __restrict__ goff, int n){
  int g = threadIdx.x;
  if (g > 64) return;
  int lo = 0, hi = n;
  while (lo < hi){ int mid = (lo + hi) >> 1; if (batch[mid] < g) lo = mid + 1; else hi = mid; }
  goff[g] = lo;
}

// ---------------- weight convert+transpose: Wt[layer][512 cols][256 k] bf16 ----------------
__global__ __launch_bounds__(256) void wt_k(const float* __restrict__ gwl, const float* __restrict__ gwr,
                                            unsigned short* __restrict__ Wt)
{
  __shared__ float t[64][65];
  int ct = blockIdx.x;
  int kt = blockIdx.y;
  int layer = blockIdx.z;
  int tid = threadIdx.x;
  int cbase = ct*64, k0 = kt*64;
  const float* src = (cbase < 256) ? (gwl + (size_t)layer*65536) : (gwr + (size_t)layer*65536);
  int csrc0 = (cbase < 256) ? cbase : cbase - 256;
  #pragma unroll
  for (int j = 0; j < 16; ++j){
    int idx = j*256 + tid;
    int kl = idx >> 6, cl = idx & 63;
    t[cl][kl] = src[(size_t)(k0 + kl)*256 + csrc0 + cl];
  }
  __syncthreads();
  #pragma unroll
  for (int j = 0; j < 16; ++j){
    int idx = j*256 + tid;
    int cl = idx >> 6, kl = idx & 63;
    Wt[(size_t)layer*131072 + (size_t)(cbase + cl)*256 + k0 + kl] = f2b(t[cl][kl]);
  }
}

// ---------------- h0 = x @ w_in + b_in (bf16 only; residual stream lives in hb) -----------
__global__ __launch_bounds__(256) void h0_k(const float* __restrict__ x, const float* __restrict__ w,
    const float* __restrict__ b, unsigned short* __restrict__ hb, int n)
{
  __shared__ float xs[16][20];
  int row0 = blockIdx.x*16, tid = threadIdx.x;
  for (int idx = tid; idx < 16*20; idx += 256){
    int r = idx/20, c = idx%20;
    int rr = row0 + r;
    xs[r][c] = (rr < n) ? x[rr*20 + c] : 0.f;
  }
  __syncthreads();
  float bj = b[tid];
  float acc[16];
  #pragma unroll
  for (int r=0;r<16;r++) acc[r] = bj;
  for (int k=0;k<20;k++){
    float wv = w[k*256 + tid];
    #pragma unroll
    for (int r=0;r<16;r++) acc[r] += xs[r][k]*wv;
  }
  #pragma unroll
  for (int r=0;r<16;r++){
    int rr = row0 + r;
    if (rr < n) hb[(size_t)rr*256 + tid] = f2b(acc[r]);
  }
}

// ---------------- bf16 MFMA GEMM (16x16x32): out = hb @ Wt^T + bias ----------------------
// LDS-staged epilogue: C -> LDS (reusing As/Bs after last barrier) -> coalesced 16B stores.
__global__ __launch_bounds__(256) void gemm_mfma_k(
    const unsigned short* __restrict__ hb,   // [n][256] bf16
    const unsigned short* __restrict__ Wt,   // [512][256] bf16 (col-major weights)
    const float* __restrict__ bl, const float* __restrict__ br,
    unsigned short* __restrict__ out,        // [n][512] bf16
    int n)
{
  __shared__ short S[16384];                 // As = S[0:8192), Bs = S[8192:16384)
  short* As = S;
  short* Bs = S + 8192;
  int tid = threadIdx.x;
  int lane = tid & 63, wid = tid >> 6;
  int wr = wid >> 1, wc = wid & 1;
  int row0 = blockIdx.x * 128;
  int col0 = blockIdx.y * 128;
  f32x4 acc[4][4] = {};

  for (int k0 = 0; k0 < 256; k0 += 64) {
    #pragma unroll
    for (int j = 0; j < 4; ++j) {
      int c = j*256 + tid;
      int r = c >> 3, q = c & 7;
      int rg = row0 + r; if (rg > n-1) rg = n-1;
      bf16x8 av = *(const bf16x8*)(hb + (size_t)rg*256 + k0 + q*8);
      bf16x8 bv = *(const bf16x8*)(Wt + (size_t)(col0 + r)*256 + k0 + q*8);
      int qs = (q ^ (r & 7)) * 8;
      *(bf16x8*)(As + r*64 + qs) = av;
      *(bf16x8*)(Bs + r*64 + qs) = bv;
    }
    __syncthreads();
    #pragma unroll
    for (int kk = 0; kk < 2; ++kk) {
      bf16x8 a[4], b[4];
      #pragma unroll
      for (int mi = 0; mi < 4; ++mi) {
        int r = wr*64 + mi*16 + (lane & 15);
        int q = (kk*4 + (lane >> 4)) ^ (r & 7);
        a[mi] = *(const bf16x8*)(As + r*64 + q*8);
      }
      #pragma unroll
      for (int ni = 0; ni < 4; ++ni) {
        int r = wc*64 + ni*16 + (lane & 15);
        int q = (kk*4 + (lane >> 4)) ^ (r & 7);
        b[ni] = *(const bf16x8*)(Bs + r*64 + q*8);
      }
      #pragma unroll
      for (int mi = 0; mi < 4; ++mi)
        #pragma unroll
        for (int ni = 0; ni < 4; ++ni)
          acc[mi][ni] = __builtin_amdgcn_mfma_f32_16x16x32_bf16(a[mi], b[ni], acc[mi][ni], 0, 0, 0);
    }
    __syncthreads();
  }

  // epilogue: bias + convert into LDS (128x128 bf16, reuses As/Bs), then coalesced stores
  const float* bias = (col0 < 256) ? bl : br;
  int cb = (col0 < 256) ? col0 : col0 - 256;
  unsigned short* Cs = (unsigned short*)S;
  #pragma unroll
  for (int ni = 0; ni < 4; ++ni) {
    int coff = wc*64 + ni*16 + (lane & 15);
    float bv = bias[cb + coff];
    #pragma unroll
    for (int mi = 0; mi < 4; ++mi) {
      int rbase = wr*64 + mi*16 + (lane >> 4)*4;
      #pragma unroll
      for (int e = 0; e < 4; ++e)
        Cs[(rbase + e)*128 + coff] = f2b(acc[mi][ni][e] + bv);
    }
  }
  __syncthreads();
  #pragma unroll
  for (int it = 0; it < 8; ++it) {           // 128 rows x 16 chunks(8 shorts) = 2048 / 256 thr
    int row = (tid >> 4) + it*16;            // 0..127
    int ch  = (tid & 15) * 8;                // short offset 0..120
    bf16x8 v = *(const bf16x8*)(Cs + row*128 + ch);
    int grow = row0 + row;
    if (grow < n) *(bf16x8*)(out + (size_t)grow*512 + col0 + ch) = v;
  }
}

// ---------------- fused GATv2: 4 edges/iter, 16 lanes/edge, per-head softmax ----------------
// Residual stream is bf16 (hb); epilogue math stays f32; last layer writes f32 to hout.
__global__ __launch_bounds__(256) void gat_agg_k(
    const unsigned short* __restrict__ xlr,  // [n][512] bf16: cols 0-255 xl, 256-511 xr
    const int* __restrict__ offs, const int2* __restrict__ ssew,
    const float* __restrict__ we, const float* __restrict__ att, const float* __restrict__ bias,
    unsigned short* __restrict__ hb, float* __restrict__ hout,
    const float* __restrict__ gw, const float* __restrict__ gb, float* __restrict__ logit, int n)
{
  int wid = blockIdx.x*4 + (threadIdx.x >> 6);
  if (wid >= n) return;
  int lane = threadIdx.x & 63;
  int g = lane >> 4, l = lane & 15;
  int c0 = l*16;                       // this lane's 16 channels (single head l>>2)

  // per-lane params (f32)
  float xr[16], wef[16], atf[16];
  {
    const unsigned short* xrp = xlr + (size_t)wid*512 + 256 + c0;
    bf16x8 r0 = *(const bf16x8*)xrp;
    bf16x8 r1 = *(const bf16x8*)(xrp + 8);
    #pragma unroll
    for (int i=0;i<8;i++){ xr[i] = b2f((unsigned short)r0[i]); xr[8+i] = b2f((unsigned short)r1[i]); }
    #pragma unroll
    for (int q=0;q<4;q++){
      float4 wv = *(const float4*)(we + c0 + q*4);
      float4 av = *(const float4*)(att + c0 + q*4);
      wef[q*4+0]=wv.x; wef[q*4+1]=wv.y; wef[q*4+2]=wv.z; wef[q*4+3]=wv.w;
      atf[q*4+0]=av.x; atf[q*4+1]=av.y; atf[q*4+2]=av.z; atf[q*4+3]=av.w;
    }
  }

  float m = -1e30f, s = 0.f;
  float a[16];
  #pragma unroll
  for (int i=0;i<16;i++) a[i] = 0.f;

  int k = offs[wid] + g, kend = offs[wid+1];
  float ewv = 0.f;
  bf16x8 xa = {0,0,0,0,0,0,0,0};
  bf16x8 xb = {0,0,0,0,0,0,0,0};
  if (k < kend){
    int2 ep = ssew[k];
    ewv = __int_as_float(ep.y);
    const unsigned short* xp = xlr + ((size_t)(unsigned)ep.x << 9) + c0;
    xa = *(const bf16x8*)xp; xb = *(const bf16x8*)(xp + 8);
  }
  while (__any(k < kend)) {
    bool act = (k < kend);
    bf16x8 ca = xa, cb = xb; float ce = ewv;
    k += 4;
    if (k < kend){
      int2 ep = ssew[k];
      ewv = __int_as_float(ep.y);
      const unsigned short* xp = xlr + ((size_t)(unsigned)ep.x << 9) + c0;
      xa = *(const bf16x8*)xp; xb = *(const bf16x8*)(xp + 8);
    }
    float xjf[16];
    #pragma unroll
    for (int i=0;i<8;i++){ xjf[i] = b2f((unsigned short)ca[i]); xjf[8+i] = b2f((unsigned short)cb[i]); }
    float p = 0.f;
    #pragma unroll
    for (int i=0;i<16;i++){
      float t = fmaf(ce, wef[i], xjf[i] + xr[i]);
      t = fmaxf(t, 0.2f*t);
      p = fmaf(t, atf[i], p);
    }
    // PER-HEAD logit: reduce over the 4 lanes sharing this head (lane bits 0,1)
    p += __shfl_xor(p, 1);
    p += __shfl_xor(p, 2);
    if (!act) p = -1e30f;              // lanes past end contribute nothing
    if (__any(p > m + 8.f)) {
      float mn = fmaxf(m, p);
      float corr = __expf(m - mn);
      float wv = act ? __expf(p - mn) : 0.f;
      s = s*corr + wv;
      #pragma unroll
      for (int i=0;i<16;i++) a[i] = fmaf(a[i], corr, wv*xjf[i]);
      m = mn;
    } else {
      float wv = act ? __expf(p - m) : 0.f;
      s += wv;
      #pragma unroll
      for (int i=0;i<16;i++) a[i] = fmaf(wv, xjf[i], a[i]);
    }
  }

  // flash-merge the 4 edge-groups per head (butterfly over lane bits 4,5; per-lane state)
  #pragma unroll
  for (int d = 16; d <= 32; d <<= 1) {
    float mo = __shfl_xor(m, d);
    float so = __shfl_xor(s, d);
    float mn = fmaxf(m, mo);
    float cs = __expf(m - mn), co = __expf(mo - mn);
    s = s*cs + so*co;
    #pragma unroll
    for (int i=0;i<16;i++){
      float ao = __shfl_xor(a[i], d);
      a[i] = fmaf(a[i], cs, ao*co);
    }
    m = mn;
  }

  // epilogue: all 64 lanes write 4 contiguous channels (wave = contiguous 0.5KB bf16)
  float inv = 1.f/(s + 1e-16f);        // this lane's head denominator
  float4 av;
  if (g == 0)      av = make_float4(a[0], a[1], a[2], a[3]);
  else if (g == 1) av = make_float4(a[4], a[5], a[6], a[7]);
  else if (g == 2) av = make_float4(a[8], a[9], a[10], a[11]);
  else             av = make_float4(a[12], a[13], a[14], a[15]);
  int cw = l*16 + g*4;
  size_t base = (size_t)wid*256 + cw;
  ushort4 hu = *(const ushort4*)(hb + base);       // bf16 residual
  float4 b4 = *(const float4*)(bias + cw);
  float4 o;
  o.x = fmaxf(b2f(hu.x) + av.x*inv + b4.x, 0.f);
  o.y = fmaxf(b2f(hu.y) + av.y*inv + b4.y, 0.f);
  o.z = fmaxf(b2f(hu.z) + av.z*inv + b4.z, 0.f);
  o.w = fmaxf(b2f(hu.w) + av.w*inv + b4.w, 0.f);
  ushort4 ob;
  ob.x = f2b(o.x); ob.y = f2b(o.y); ob.z = f2b(o.z); ob.w = f2b(o.w);
  *(ushort4*)(hb + base) = ob;
  if (hout) *(float4*)(hout + base) = o;           // last layer: f32 h output from registers

  // fused pooling gate logit (only on pooling layers): dot(h_row, gate_w) over 256 ch
  if (gw) {
    float4 gv = *(const float4*)(gw + cw);
    float p = o.x*gv.x + o.y*gv.y + o.z*gv.z + o.w*gv.w;
    p += __shfl_xor(p, 1);
    p += __shfl_xor(p, 2);
    p += __shfl_xor(p, 4);
    p += __shfl_xor(p, 8);
    p += __shfl_xor(p, 16);
    p += __shfl_xor(p, 32);
    if (lane == 0) logit[wid] = p + gb[0];
  }
}

// ---------------- pooling stage 1: per-slice online-softmax partials ----------------
// part layout per (g,slice): [0]=m, [1]=s, [2..257]=acc  (260 floats stride)
__global__ __launch_bounds__(256) void pool1_k(const unsigned short* __restrict__ hb,
    const float* __restrict__ logit, const int* __restrict__ goff, float* __restrict__ part)
{
  __shared__ float red[256];
  int g = blockIdx.x >> 3, sl = blockIdx.x & 7;
  int b0 = goff[g], b1 = goff[g+1];
  int len = b1 - b0;
  int per = (len + 7) >> 3;
  int r0 = b0 + sl*per;
  int r1 = r0 + per; if (r1 > b1) r1 = b1;
  int tid = threadIdx.x;
  float* P = part + (size_t)blockIdx.x * 260;

  float lm = -1e30f;
  for (int i = r0 + tid; i < r1; i += 256) lm = fmaxf(lm, logit[i]);
  red[tid] = lm;
  __syncthreads();
  for (int s = 128; s > 0; s >>= 1){
    if (tid < s) red[tid] = fmaxf(red[tid], red[tid+s]);
    __syncthreads();
  }
  float m = red[0];
  __syncthreads();                       // all threads read red[0] before reuse
  float sw = 0.f;
  for (int i = r0 + tid; i < r1; i += 256) sw += __expf(logit[i] - m);
  red[tid] = sw;
  __syncthreads();
  for (int s = 128; s > 0; s >>= 1){
    if (tid < s) red[tid] += red[tid+s];
    __syncthreads();
  }
  float ssum = red[0];

  float acc = 0.f;
  for (int i = r0; i < r1; ++i)
    acc += __expf(logit[i] - m) * b2f(hb[(size_t)i*256 + tid]);
  P[2 + tid] = acc;
  if (tid == 0){ P[0] = m; P[1] = ssum; }
}

// ---------------- pooling stage 2 FUSED with nn Linear: zcat_blk[g] = pool(g) @ W + b -----
__global__ __launch_bounds__(256) void pool2nn_k(const float* __restrict__ part,
    const float* __restrict__ W, const float* __restrict__ b,
    float* __restrict__ out, int ostride)
{
  __shared__ float hs[256];
  int g = blockIdx.x, tid = threadIdx.x;
  const float* P = part + (size_t)g*8*260;
  float M = -1e30f;
  #pragma unroll
  for (int s = 0; s < 8; ++s) M = fmaxf(M, P[s*260]);
  float den = 0.f, acc = 0.f;
  #pragma unroll
  for (int s = 0; s < 8; ++s){
    float c = __expf(P[s*260] - M);
    den += P[s*260 + 1] * c;
    acc += P[s*260 + 2 + tid] * c;
  }
  hs[tid] = acc/(den + 1e-16f);
  __syncthreads();
  float o = b[tid];
  for (int k = 0; k < 256; ++k) o = fmaf(hs[k], W[k*256 + tid], o);
  out[(size_t)g*ostride + tid] = o;
}

// ---------------- fused output MLP: enc = relu(zcat @ ow1 + ob1) @ ow2 + ob2 --------------
__global__ __launch_bounds__(256) void outmlp_k(const float* __restrict__ zcat,
    const float* __restrict__ ow1, const float* __restrict__ ob1,
    const float* __restrict__ ow2, const float* __restrict__ ob2,
    float* __restrict__ out)
{
  __shared__ float zr[768];
  __shared__ float t1[256];
  int row = blockIdx.x, tid = threadIdx.x;
  for (int i = tid; i < 768; i += 256) zr[i] = zcat[(size_t)row*768 + i];
  __syncthreads();
  float a = ob1[tid];
  for (int k = 0; k < 768; ++k) a = fmaf(zr[k], ow1[k*256 + tid], a);
  t1[tid] = fmaxf(a, 0.f);
  __syncthreads();
  float o = ob2[tid];
  for (int k = 0; k < 256; ++k) o = fmaf(t1[k], ow2[k*256 + tid], o);
  out[(size_t)row*256 + tid] = o;
}

extern "C" void kernel_launch(void* const* d_in, const int* in_sizes, int n_in,
                              void* d_out, int out_size, void* d_ws, size_t ws_size,
                              hipStream_t stream)
{
  const float* x     = (const float*)d_in[0];
  const float* pos   = (const float*)d_in[1];
  const int*   ei    = (const int*)d_in[2];
  const int*   batch = (const int*)d_in[3];
  const float* mw1   = (const float*)d_in[4];
  const float* mb1   = (const float*)d_in[5];
  const float* mw2   = (const float*)d_in[6];
  const float* mb2   = (const float*)d_in[7];
  const float* w_in  = (const float*)d_in[8];
  const float* b_in  = (const float*)d_in[9];
  const float* gwl   = (const float*)d_in[10];
  const float* gbl   = (const float*)d_in[11];
  const float* gwr   = (const float*)d_in[12];
  const float* gbr   = (const float*)d_in[13];
  const float* gwe   = (const float*)d_in[14];
  const float* gatt  = (const float*)d_in[15];
  const float* gbias = (const float*)d_in[16];
  const float* gate_w= (const float*)d_in[17];
  const float* gate_b= (const float*)d_in[18];
  const float* nn_w  = (const float*)d_in[19];
  const float* nn_b  = (const float*)d_in[20];
  const float* ow1   = (const float*)d_in[21];
  const float* ob1   = (const float*)d_in[22];
  const float* ow2   = (const float*)d_in[23];
  const float* ob2   = (const float*)d_in[24];

  const int N = in_sizes[0] / F_IN;
  const int E = in_sizes[2] / 2;

  char* ws = (char*)d_ws;
  size_t woff = 0;
  auto alloc = [&](size_t bytes) -> void* {
    void* p = ws + woff;
    woff = (woff + bytes + 255) & ~(size_t)255;
    return p;
  };
  float* ew    = (float*)alloc((size_t)E*4);
  int*   cnt   = (int*)  alloc((size_t)N*4);
  int*   offs  = (int*)  alloc((size_t)(N+1)*4);
  int*   cur   = (int*)  alloc((size_t)N*4);
  int*   bsum  = (int*)  alloc(512*4);
  int*   bpre  = (int*)  alloc(512*4);
  int2*  ssew  = (int2*) alloc((size_t)E*8);
  unsigned short* hb  = (unsigned short*)alloc((size_t)N*DDIM*2);
  unsigned short* xlr = (unsigned short*)alloc((size_t)N*512*2);
  unsigned short* Wt  = (unsigned short*)alloc((size_t)6*512*256*2);
  float* logit = (float*)alloc((size_t)N*4);
  int*   goff  = (int*)  alloc(68*4);
  // pooling-phase scratch ALIASES the dead edge-MLP buffer (ew: E*4 = 3.2 MB;
  // ew is only live between edge_prep_k and scatter_k; these are only live in
  // the pooling phase).
  float* part  = ew;                       // 512*260   = 133120 floats
  float* zcat  = ew + 149504;              // 64*768    =  49152 floats
  (void)ws_size; (void)n_in; (void)out_size;

  hipMemsetAsync(cnt, 0, (size_t)N*4, stream);

  int eb = (E + 255)/256;
  edge_prep_k<<<eb, 256, 0, stream>>>(ei, pos, mw1, mb1, mw2, mb2, ew, cnt, E);
  int nb = (N + 511)/512;
  scan1_k<<<nb, 512, 0, stream>>>(cnt, offs, bsum, N);
  scan2_k<<<1, 512, 0, stream>>>(bsum, bpre, nb);
  scan3_k<<<nb, 512, 0, stream>>>(offs, cur, bpre, N, E);
  scatter_k<<<eb, 256, 0, stream>>>(ei, ew, cur, ssew, E);

  gseg_k<<<1, 128, 0, stream>>>(batch, goff, N);
  wt_k<<<dim3(8,4,6), 256, 0, stream>>>(gwl, gwr, Wt);

  h0_k<<<(N + 15)/16, 256, 0, stream>>>(x, w_in, b_in, hb, N);

  int gx = (N + 127)/128;
  int wavegrid = (N + 3)/4;
  for (int i = 0; i < 6; ++i) {
    gemm_mfma_k<<<dim3(gx, 4), 256, 0, stream>>>(hb, Wt + (size_t)i*131072,
        gbl + i*256, gbr + i*256, xlr, N);
    float* hout = (i == 5) ? (float*)d_out : (float*)nullptr;
    int blk = i >> 1;
    const float* gwp = (i & 1) ? (gate_w + blk*256) : (const float*)nullptr;
    const float* gbp = (i & 1) ? (gate_b + blk) : (const float*)nullptr;
    gat_agg_k<<<wavegrid, 256, 0, stream>>>(xlr, offs, ssew,
        gwe + i*256, gatt + i*256, gbias + i*256, hb, hout, gwp, gbp, logit, N);
    if (i & 1) {
      pool1_k<<<512, 256, 0, stream>>>(hb, logit, goff, part);
      pool2nn_k<<<64, 256, 0, stream>>>(part, nn_w + (size_t)blk*65536,
          nn_b + blk*256, zcat + blk*256, 768);
    }
  }
  outmlp_k<<<64, 256, 0, stream>>>(zcat, ow1, ob1, ow2, ob2, (float*)d_out + (size_t)N*DDIM);
}